// Round 9
// baseline (161.626 us; speedup 1.0000x reference)
//
#include <hip/hip_runtime.h>

// B=4, L=2048, H=8, E=D=64, float32. LocalLogSymmetryMask at L=2048 allows per
// row i exactly the columns j = i + D[c] with 0 <= j < L, where D is the
// 47-entry constant offset set below (window -5..+5 plus +-(5+F),
// F(m)=(3^(m+1))>>(m+1) = {1,2,3,5,7,11,17,25,38,57,86,129,194,291,437,656,
// 985,1477}); range-clipping is exactly equivalent to the reference's edge
// branches + monotone `break`s. -> sparse attention over <=47 candidates.
//
// Round-9 structure: identical math to round 8, but memory-level parallelism
// is FORCED: all 25 global loads (12 K + Q + 12 V) are issued back-to-back
// and then pinned live via empty asm reads (data dependency -> the backend
// cannot re-sink loads next to uses; VGPR was stuck at 36 for two rounds
// proving it did exactly that). After the pins everything is pure VALU.
// Trade: ~120 VGPRs -> ~4 waves/SIMD, but outstanding reqs/CU ~400 vs ~60.

#define KB 4
#define KL 2048
#define KH 8
#define KE 64
#define KWAVES 4
#define KROWS (KB * KL * KH)
#define KBLOCKS (KROWS / KWAVES)       // 16384
#define KROWSTRIDE (KH * KE)           // 512 floats between consecutive j

// Candidate offsets: c 0..10 window (c-5); 11..28 left logs -(5+F);
// 29..46 right logs +(5+F); 47 dummy (always out of range).
static constexpr int kOff[48] = {
    -5, -4, -3, -2, -1, 0, 1, 2, 3, 4, 5,
    -6, -7, -8, -10, -12, -16, -22, -30, -43, -62, -91, -134, -199, -296,
    -442, -661, -990, -1482,
    6, 7, 8, 10, 12, 16, 22, 30, 43, 62, 91, 134, 199, 296, 442, 661, 990,
    1482,
    1 << 20};

#define PIN4(F) asm volatile("" :: "v"(F.x), "v"(F.y), "v"(F.z), "v"(F.w))

__global__ __launch_bounds__(256, 4)
void MaskAttention_20572893347881_kernel(
    const float* __restrict__ q, const float* __restrict__ k,
    const float* __restrict__ v, float* __restrict__ out) {
    const int tid  = (int)threadIdx.x;
    const int lane = tid & 63;
    const int wave = tid >> 6;
    const int g    = lane >> 4;   // candidate group 0..3
    const int e4   = lane & 15;   // element-quad index 0..15

    // XCD-locality swizzle (bijection on [0,16384)): each XCD's blocks cover
    // a contiguous i-range -> its K/V working set fits the private 4MB L2.
    const int p  = (int)blockIdx.x;
    const int l  = (p & 7) * (KBLOCKS / 8) + (p >> 3);
    const int r  = l * KWAVES + wave;              // [0, 65536)
    const int i  = r & (KL - 1);
    const int h  = (r >> 11) & (KH - 1);
    const int b  = r >> 14;

    const size_t base    = (size_t)b * (KL * KH * KE) + (size_t)h * KE;
    const size_t rowbase = base + (size_t)i * KROWSTRIDE;

    const bool g1 = (g & 1) != 0;
    const bool g2 = (g & 2) != 0;

    // ---- candidate columns from compile-time offsets (no shuffles) ----
    int  jc[12];
    bool ok[12];
#pragma unroll
    for (int t = 0; t < 12; ++t) {
        const int a0 = kOff[4 * t + 0], a1 = kOff[4 * t + 1];
        const int a2 = kOff[4 * t + 2], a3 = kOff[4 * t + 3];
        const int dd = g1 ? (g2 ? a3 : a1) : (g2 ? a2 : a0);
        const int j  = i + dd;
        ok[t] = ((unsigned)j) < (unsigned)KL;
        jc[t] = ok[t] ? j : 0;
    }

    const float* kp = k + base + e4 * 4;
    const float* vp = v + base + e4 * 4;

    // ---- issue ALL 25 loads back-to-back, then pin them live ----
    float4 kf[12], vf[12];
#pragma unroll
    for (int t = 0; t < 12; ++t)
        kf[t] = *(const float4*)(kp + (size_t)jc[t] * KROWSTRIDE);
    float4 qf = *(const float4*)(q + rowbase + e4 * 4);
#pragma unroll
    for (int t = 0; t < 12; ++t)
        vf[t] = *(const float4*)(vp + (size_t)jc[t] * KROWSTRIDE);

#pragma unroll
    for (int t = 0; t < 12; ++t) PIN4(kf[t]);
    PIN4(qf);
#pragma unroll
    for (int t = 0; t < 12; ++t) PIN4(vf[t]);

    qf.x *= 0.125f; qf.y *= 0.125f; qf.z *= 0.125f; qf.w *= 0.125f;

    // ---- scores: partial dots + 4-step butterfly within 16-lane group ----
    float s[12];
#pragma unroll
    for (int t = 0; t < 12; ++t)
        s[t] = qf.x * kf[t].x + qf.y * kf[t].y + qf.z * kf[t].z + qf.w * kf[t].w;
#pragma unroll
    for (int t = 0; t < 12; ++t) {
        float d0 = s[t];
        d0 += __shfl_xor(d0, 1, 64);
        d0 += __shfl_xor(d0, 2, 64);
        d0 += __shfl_xor(d0, 4, 64);
        d0 += __shfl_xor(d0, 8, 64);
        s[t] = ok[t] ? d0 : -1e30f;
    }

    // ---- softmax in registers (cross-group via 2 shfl_xor) ----
    float m = s[0];
#pragma unroll
    for (int t = 1; t < 12; ++t) m = fmaxf(m, s[t]);
    m = fmaxf(m, __shfl_xor(m, 16, 64));
    m = fmaxf(m, __shfl_xor(m, 32, 64));
    float d = 0.f;
    float pr[12];
#pragma unroll
    for (int t = 0; t < 12; ++t) {
        pr[t] = __expf(s[t] - m);   // -1e30-m underflows to exactly 0
        d += pr[t];
    }
    d += __shfl_xor(d, 16, 64);
    d += __shfl_xor(d, 32, 64);
    const float inv = 1.f / d;      // diagonal always valid -> d >= 1

    // ---- PV accumulate + cross-group reduce ----
    float4 acc = make_float4(0.f, 0.f, 0.f, 0.f);
#pragma unroll
    for (int t = 0; t < 12; ++t) {
        acc.x += pr[t] * vf[t].x;
        acc.y += pr[t] * vf[t].y;
        acc.z += pr[t] * vf[t].z;
        acc.w += pr[t] * vf[t].w;
    }
    acc.x += __shfl_xor(acc.x, 16, 64);
    acc.y += __shfl_xor(acc.y, 16, 64);
    acc.z += __shfl_xor(acc.z, 16, 64);
    acc.w += __shfl_xor(acc.w, 16, 64);
    acc.x += __shfl_xor(acc.x, 32, 64);
    acc.y += __shfl_xor(acc.y, 32, 64);
    acc.z += __shfl_xor(acc.z, 32, 64);
    acc.w += __shfl_xor(acc.w, 32, 64);

    if (lane < 16) {
        float4 o = make_float4(acc.x * inv, acc.y * inv, acc.z * inv, acc.w * inv);
        *(float4*)(out + rowbase + e4 * 4) = o;
    }
}

extern "C" void kernel_launch(void* const* d_in, const int* in_sizes, int n_in,
                              void* d_out, int out_size, void* d_ws, size_t ws_size,
                              hipStream_t stream) {
    (void)in_sizes; (void)n_in; (void)out_size; (void)d_ws; (void)ws_size;
    const float* q = (const float*)d_in[0];
    const float* k = (const float*)d_in[1];
    const float* v = (const float*)d_in[2];
    // d_in[3] (mask) unused: LocalLogSymmetryMask is a deterministic function
    // of L and is recomputed analytically in-kernel.
    float* out = (float*)d_out;

    hipLaunchKernelGGL(MaskAttention_20572893347881_kernel,
                       dim3(KBLOCKS), dim3(KWAVES * 64), 0, stream,
                       q, k, v, out);
}

// Round 10
// 147.470 us; speedup vs baseline: 1.0960x; 1.0960x over previous
//
#include <hip/hip_runtime.h>

// B=4, L=2048, H=8, E=D=64, float32. LocalLogSymmetryMask at L=2048 allows per
// row i exactly the columns j = i + D[c] with 0 <= j < L, where D is the
// 47-entry constant offset set below (window -5..+5 plus +-(5+F),
// F(m)=(3^(m+1))>>(m+1) = {1,2,3,5,7,11,17,25,38,57,86,129,194,291,437,656,
// 985,1477}); range-clipping is exactly equivalent to the reference's edge
// branches + monotone `break`s. -> sparse attention over <=47 candidates.
//
// Round-10 structure: ONE WAVE PER BLOCK (64 threads). b/h/i are now
// block-uniform -> the compiler scalarizes all base addresses into SGPRs and
// emits saddr-form global_load_dwordx4 with a single 32-bit voffset, cutting
// the dominant VALU cost (25 x ~7 VALU of 64-bit vector address math in
// rounds 7-9, VGPR stuck at 36, VALUBusy ~60% of the wall). Clamping is a
// single v_min_u32 (invalid candidates read row 2047; their weight is exactly
// 0 after the -1e30 mask). Lesson from R9: never trade occupancy for MLP
// here -- many cheap waves win.
// Wave = 4 groups x 16 lanes; group g owns candidates c=4t+g (t=0..11);
// lane e4=lane&15 owns elements 4*e4..4*e4+3 of each 64-float row.
// XCD swizzle: physical block p -> row r=(p&7)*8192+(p>>3), so each XCD works
// a contiguous i-range (keeps FETCH at ~24.6 MB vs 136 MB unswizzled).

#define KB 4
#define KL 2048
#define KH 8
#define KE 64
#define KROWS (KB * KL * KH)           // 65536 = grid size (1 wave each)
#define KROWSTRIDE (KH * KE)           // 512 floats between consecutive j

// Candidate offsets: c 0..10 window (c-5); 11..28 left logs -(5+F);
// 29..46 right logs +(5+F); 47 dummy (always out of range).
static constexpr int kOff[48] = {
    -5, -4, -3, -2, -1, 0, 1, 2, 3, 4, 5,
    -6, -7, -8, -10, -12, -16, -22, -30, -43, -62, -91, -134, -199, -296,
    -442, -661, -990, -1482,
    6, 7, 8, 10, 12, 16, 22, 30, 43, 62, 91, 134, 199, 296, 442, 661, 990,
    1482,
    1 << 20};

__global__ __launch_bounds__(64)
void MaskAttention_20572893347881_kernel(
    const float* __restrict__ q, const float* __restrict__ k,
    const float* __restrict__ v, float* __restrict__ out) {
    const int lane = (int)threadIdx.x;   // 0..63
    const int g    = lane >> 4;          // candidate group 0..3
    const int e4   = lane & 15;          // element-quad index 0..15

    // XCD-locality swizzle (bijection on [0,65536)); all block-uniform.
    const int p = (int)blockIdx.x;
    const int r = (p & 7) * (KROWS / 8) + (p >> 3);
    const int i = r & (KL - 1);
    const int h = (r >> 11) & (KH - 1);
    const int b = r >> 14;

    // Block-uniform base pointers (SGPR-resident after scalarization).
    const float* __restrict__ kb = k + (size_t)b * (KL * KH * KE) + (size_t)h * KE;
    const float* __restrict__ vb = v + (size_t)b * (KL * KH * KE) + (size_t)h * KE;
    const size_t rowoff = (size_t)i * KROWSTRIDE + (size_t)e4 * 4;

    const bool g1 = (g & 1) != 0;
    const bool g2 = (g & 2) != 0;

    // ---- candidate row offsets (32-bit, min-clamped; no cndmask chains) ----
    unsigned jro[12];   // clamped row * KROWSTRIDE + e4*4 (element offset)
    bool     ok[12];
    const unsigned co = (unsigned)(e4 * 4);
#pragma unroll
    for (int t = 0; t < 12; ++t) {
        const int a0 = kOff[4 * t + 0], a1 = kOff[4 * t + 1];
        const int a2 = kOff[4 * t + 2], a3 = kOff[4 * t + 3];
        const int dd = g1 ? (g2 ? a3 : a1) : (g2 ? a2 : a0);
        const unsigned ju = (unsigned)(i + dd);
        ok[t] = ju < (unsigned)KL;
        const unsigned jcl = ju < (unsigned)KL ? ju : (unsigned)(KL - 1);
        jro[t] = jcl * (unsigned)KROWSTRIDE + co;
    }

    // ---- K loads + Q load ----
    float4 kf[12];
#pragma unroll
    for (int t = 0; t < 12; ++t)
        kf[t] = *(const float4*)(kb + jro[t]);
    float4 qf = *(const float4*)(q + (size_t)b * (KL * KH * KE) + (size_t)h * KE + rowoff);
    qf.x *= 0.125f; qf.y *= 0.125f; qf.z *= 0.125f; qf.w *= 0.125f;

    // ---- independent partial dots (frees kf) ----
    float s[12];
#pragma unroll
    for (int t = 0; t < 12; ++t)
        s[t] = qf.x * kf[t].x + qf.y * kf[t].y + qf.z * kf[t].z + qf.w * kf[t].w;

    // ---- V loads issued; butterflies/softmax overlap their latency ----
    float4 vf[12];
#pragma unroll
    for (int t = 0; t < 12; ++t)
        vf[t] = *(const float4*)(vb + jro[t]);

    // ---- dot butterflies within 16-lane group ----
#pragma unroll
    for (int t = 0; t < 12; ++t) {
        float d0 = s[t];
        d0 += __shfl_xor(d0, 1, 64);
        d0 += __shfl_xor(d0, 2, 64);
        d0 += __shfl_xor(d0, 4, 64);
        d0 += __shfl_xor(d0, 8, 64);
        s[t] = ok[t] ? d0 : -1e30f;
    }

    // ---- softmax in registers (cross-group via 2 shfl_xor) ----
    float m = s[0];
#pragma unroll
    for (int t = 1; t < 12; ++t) m = fmaxf(m, s[t]);
    m = fmaxf(m, __shfl_xor(m, 16, 64));
    m = fmaxf(m, __shfl_xor(m, 32, 64));
    float d = 0.f;
    float pr[12];
#pragma unroll
    for (int t = 0; t < 12; ++t) {
        pr[t] = __expf(s[t] - m);   // -1e30-m underflows to exactly 0
        d += pr[t];
    }
    d += __shfl_xor(d, 16, 64);
    d += __shfl_xor(d, 32, 64);
    const float inv = 1.f / d;      // diagonal always valid -> d >= 1

    // ---- PV accumulate + cross-group reduce ----
    float4 acc = make_float4(0.f, 0.f, 0.f, 0.f);
#pragma unroll
    for (int t = 0; t < 12; ++t) {
        acc.x += pr[t] * vf[t].x;
        acc.y += pr[t] * vf[t].y;
        acc.z += pr[t] * vf[t].z;
        acc.w += pr[t] * vf[t].w;
    }
    acc.x += __shfl_xor(acc.x, 16, 64);
    acc.y += __shfl_xor(acc.y, 16, 64);
    acc.z += __shfl_xor(acc.z, 16, 64);
    acc.w += __shfl_xor(acc.w, 16, 64);
    acc.x += __shfl_xor(acc.x, 32, 64);
    acc.y += __shfl_xor(acc.y, 32, 64);
    acc.z += __shfl_xor(acc.z, 32, 64);
    acc.w += __shfl_xor(acc.w, 32, 64);

    if (lane < 16) {
        float4 o = make_float4(acc.x * inv, acc.y * inv, acc.z * inv, acc.w * inv);
        *(float4*)(out + (size_t)b * (KL * KH * KE) + (size_t)h * KE + rowoff) = o;
    }
}

extern "C" void kernel_launch(void* const* d_in, const int* in_sizes, int n_in,
                              void* d_out, int out_size, void* d_ws, size_t ws_size,
                              hipStream_t stream) {
    (void)in_sizes; (void)n_in; (void)out_size; (void)d_ws; (void)ws_size;
    const float* q = (const float*)d_in[0];
    const float* k = (const float*)d_in[1];
    const float* v = (const float*)d_in[2];
    // d_in[3] (mask) unused: LocalLogSymmetryMask is a deterministic function
    // of L and is recomputed analytically in-kernel.
    float* out = (float*)d_out;

    hipLaunchKernelGGL(MaskAttention_20572893347881_kernel,
                       dim3(KROWS), dim3(64), 0, stream,
                       q, k, v, out);
}

// Round 11
// 143.496 us; speedup vs baseline: 1.1264x; 1.0277x over previous
//
#include <hip/hip_runtime.h>

// B=4, L=2048, H=8, E=D=64, float32. LocalLogSymmetryMask at L=2048 allows per
// row i exactly the columns j = i + D[c] with 0 <= j < L, where D is the
// 47-entry constant offset set below (window -5..+5 plus +-(5+F),
// F(m)=(3^(m+1))>>(m+1) = {1,2,3,5,7,11,17,25,38,57,86,129,194,291,437,656,
// 985,1477}); range-clipping is exactly equivalent to the reference's edge
// branches + monotone `break`s. -> sparse attention over <=47 candidates.
//
// Round-11: combine R8's L1 locality with R10's scalar addressing.
//  * Block = 256 = 4 waves handling ADJACENT i (same b,h) -> the 4 waves
//    share a CU and its L1, so the window band (11/47 of all line traffic,
//    ~10/11 rows shared between neighboring i) L1-hits across waves.
//    (R10's 64-thread blocks scattered adjacent i across CUs -- lost reuse.)
//  * wave id forced uniform via readfirstlane -> i/h/b stay scalar -> K/V/Q
//    loads keep the saddr form (s[base] + 32-bit voffset), which was R10's
//    VALU win (VALUBusy 60->51%, VGPR 36->32).
//  * Q load issued BEFORE the K loads (dots need Q and kf[0] first; it was
//    last in the queue -> full extra round-trip on the critical path).
//  * min-clamp for invalid candidates (read row 2047, weight exactly 0).
// Wave = 4 groups x 16 lanes; group g owns candidates c=4t+g (t=0..11);
// lane e4=lane&15 owns elements 4*e4..4*e4+3 of each 64-float row.
// XCD swizzle keeps each XCD on a contiguous i-range (FETCH 24.6 MB).

#define KB 4
#define KL 2048
#define KH 8
#define KE 64
#define KWAVES 4
#define KROWS (KB * KL * KH)
#define KBLOCKS (KROWS / KWAVES)       // 16384
#define KROWSTRIDE (KH * KE)           // 512 floats between consecutive j

// Candidate offsets: c 0..10 window (c-5); 11..28 left logs -(5+F);
// 29..46 right logs +(5+F); 47 dummy (always out of range).
static constexpr int kOff[48] = {
    -5, -4, -3, -2, -1, 0, 1, 2, 3, 4, 5,
    -6, -7, -8, -10, -12, -16, -22, -30, -43, -62, -91, -134, -199, -296,
    -442, -661, -990, -1482,
    6, 7, 8, 10, 12, 16, 22, 30, 43, 62, 91, 134, 199, 296, 442, 661, 990,
    1482,
    1 << 20};

__global__ __launch_bounds__(256)
void MaskAttention_20572893347881_kernel(
    const float* __restrict__ q, const float* __restrict__ k,
    const float* __restrict__ v, float* __restrict__ out) {
    const int tid  = (int)threadIdx.x;
    const int lane = tid & 63;
    const int g    = lane >> 4;          // candidate group 0..3
    const int e4   = lane & 15;          // element-quad index 0..15
    // Force wave id into an SGPR: i/h/b become provably wave-uniform ->
    // scalar base addresses + saddr-form loads.
    const int wave = __builtin_amdgcn_readfirstlane(tid >> 6);

    // XCD-locality swizzle (bijection on [0,16384) blocks).
    const int p = (int)blockIdx.x;
    const int l = (p & 7) * (KBLOCKS / 8) + (p >> 3);
    const int r = l * KWAVES + wave;     // [0, 65536); adjacent i in one block
    const int i = r & (KL - 1);
    const int h = (r >> 11) & (KH - 1);
    const int b = r >> 14;

    const size_t hb   = (size_t)b * (KL * KH * KE) + (size_t)h * KE;
    const float* __restrict__ kb = k + hb;
    const float* __restrict__ vb = v + hb;
    const size_t rowoff = (size_t)i * KROWSTRIDE + (size_t)e4 * 4;

    const bool g1 = (g & 1) != 0;
    const bool g2 = (g & 2) != 0;

    // ---- candidate row offsets (32-bit, min-clamped) ----
    unsigned jro[12];
    bool     ok[12];
    const unsigned co = (unsigned)(e4 * 4);
#pragma unroll
    for (int t = 0; t < 12; ++t) {
        const int a0 = kOff[4 * t + 0], a1 = kOff[4 * t + 1];
        const int a2 = kOff[4 * t + 2], a3 = kOff[4 * t + 3];
        const int dd = g1 ? (g2 ? a3 : a1) : (g2 ? a2 : a0);
        const unsigned ju = (unsigned)(i + dd);
        ok[t] = ju < (unsigned)KL;
        const unsigned jcl = ju < (unsigned)KL ? ju : (unsigned)(KL - 1);
        jro[t] = jcl * (unsigned)KROWSTRIDE + co;
    }

    // ---- Q first (critical path), then all K loads ----
    float4 qf = *(const float4*)(q + hb + rowoff);
    float4 kf[12];
#pragma unroll
    for (int t = 0; t < 12; ++t)
        kf[t] = *(const float4*)(kb + jro[t]);
    qf.x *= 0.125f; qf.y *= 0.125f; qf.z *= 0.125f; qf.w *= 0.125f;

    // ---- independent partial dots (frees kf) ----
    float s[12];
#pragma unroll
    for (int t = 0; t < 12; ++t)
        s[t] = qf.x * kf[t].x + qf.y * kf[t].y + qf.z * kf[t].z + qf.w * kf[t].w;

    // ---- V loads issued; butterflies/softmax overlap their latency ----
    float4 vf[12];
#pragma unroll
    for (int t = 0; t < 12; ++t)
        vf[t] = *(const float4*)(vb + jro[t]);

    // ---- dot butterflies within 16-lane group ----
#pragma unroll
    for (int t = 0; t < 12; ++t) {
        float d0 = s[t];
        d0 += __shfl_xor(d0, 1, 64);
        d0 += __shfl_xor(d0, 2, 64);
        d0 += __shfl_xor(d0, 4, 64);
        d0 += __shfl_xor(d0, 8, 64);
        s[t] = ok[t] ? d0 : -1e30f;
    }

    // ---- softmax in registers (cross-group via 2 shfl_xor) ----
    float m = s[0];
#pragma unroll
    for (int t = 1; t < 12; ++t) m = fmaxf(m, s[t]);
    m = fmaxf(m, __shfl_xor(m, 16, 64));
    m = fmaxf(m, __shfl_xor(m, 32, 64));
    float d = 0.f;
    float pr[12];
#pragma unroll
    for (int t = 0; t < 12; ++t) {
        pr[t] = __expf(s[t] - m);   // -1e30-m underflows to exactly 0
        d += pr[t];
    }
    d += __shfl_xor(d, 16, 64);
    d += __shfl_xor(d, 32, 64);
    const float inv = 1.f / d;      // diagonal always valid -> d >= 1

    // ---- PV accumulate + cross-group reduce ----
    float4 acc = make_float4(0.f, 0.f, 0.f, 0.f);
#pragma unroll
    for (int t = 0; t < 12; ++t) {
        acc.x += pr[t] * vf[t].x;
        acc.y += pr[t] * vf[t].y;
        acc.z += pr[t] * vf[t].z;
        acc.w += pr[t] * vf[t].w;
    }
    acc.x += __shfl_xor(acc.x, 16, 64);
    acc.y += __shfl_xor(acc.y, 16, 64);
    acc.z += __shfl_xor(acc.z, 16, 64);
    acc.w += __shfl_xor(acc.w, 16, 64);
    acc.x += __shfl_xor(acc.x, 32, 64);
    acc.y += __shfl_xor(acc.y, 32, 64);
    acc.z += __shfl_xor(acc.z, 32, 64);
    acc.w += __shfl_xor(acc.w, 32, 64);

    if (lane < 16) {
        float4 o = make_float4(acc.x * inv, acc.y * inv, acc.z * inv, acc.w * inv);
        *(float4*)(out + hb + rowoff) = o;
    }
}

extern "C" void kernel_launch(void* const* d_in, const int* in_sizes, int n_in,
                              void* d_out, int out_size, void* d_ws, size_t ws_size,
                              hipStream_t stream) {
    (void)in_sizes; (void)n_in; (void)out_size; (void)d_ws; (void)ws_size;
    const float* q = (const float*)d_in[0];
    const float* k = (const float*)d_in[1];
    const float* v = (const float*)d_in[2];
    // d_in[3] (mask) unused: LocalLogSymmetryMask is a deterministic function
    // of L and is recomputed analytically in-kernel.
    float* out = (float*)d_out;

    hipLaunchKernelGGL(MaskAttention_20572893347881_kernel,
                       dim3(KBLOCKS), dim3(KWAVES * 64), 0, stream,
                       q, k, v, out);
}